// Round 3
// baseline (562.781 us; speedup 1.0000x reference)
//
#include <hip/hip_runtime.h>

#define DD 64
#define KK 1024
#define NN 65536   // 16 * 4096 tokens

// ws layout:
//   [0, 256KB)        : eT    [K][D] f32  (transposed codebook, rows 256B contiguous)
//   [256KB, 260KB)    : enorm [K]    f32
//   [260KB, 516KB)    : flags [N]    int  (1 = near-tie, rescore in f64)

__global__ __launch_bounds__(256) void vq_prep(const float* __restrict__ embed,
                                               float* __restrict__ eT,
                                               float* __restrict__ enorm) {
    int k = blockIdx.x * 256 + threadIdx.x;
    if (k >= KK) return;
    float s = 0.f;
#pragma unroll
    for (int d = 0; d < DD; ++d) {
        float v = embed[d * KK + k];          // coalesced across lanes
        eT[(size_t)k * DD + d] = v;
        s = fmaf(v, v, s);
    }
    enorm[k] = s;
}

__global__ __launch_bounds__(256) void vq_pass1(const float* __restrict__ inp,
                                                const float* __restrict__ eT,
                                                const float* __restrict__ enormp,
                                                float* __restrict__ outQ,
                                                float* __restrict__ outDiff,
                                                float* __restrict__ outInd,
                                                int* __restrict__ flags) {
    int n = blockIdx.x * 256 + threadIdx.x;   // one lane per token

    // x row -> 64 VGPRs
    float x[DD];
    const float4* xp = (const float4*)(inp + (size_t)n * DD);
#pragma unroll
    for (int i = 0; i < DD / 4; ++i) {
        float4 v = xp[i];
        x[4 * i + 0] = v.x; x[4 * i + 1] = v.y;
        x[4 * i + 2] = v.z; x[4 * i + 3] = v.w;
    }

    float best1 = 3.4e38f, best2 = 3.4e38f;
    int k1 = 0;
    for (int k = 0; k < KK; ++k) {
        const float* __restrict__ e = eT + (size_t)k * DD;  // wave-uniform -> s_load
        float a0 = 0.f, a1 = 0.f, a2 = 0.f, a3 = 0.f;
#pragma unroll
        for (int d = 0; d < DD; d += 4) {
            a0 = fmaf(x[d + 0], e[d + 0], a0);
            a1 = fmaf(x[d + 1], e[d + 1], a1);
            a2 = fmaf(x[d + 2], e[d + 2], a2);
            a3 = fmaf(x[d + 3], e[d + 3], a3);
        }
        float dot  = (a0 + a1) + (a2 + a3);
        float dist = fmaf(-2.f, dot, enormp[k]);   // ||e||^2 - 2 x.e  (||x||^2 constant)
        bool lt1 = dist < best1;                   // strict: keep first min like np.argmin
        bool lt2 = dist < best2;
        float nb2 = lt1 ? best1 : (lt2 ? dist : best2);
        best1 = lt1 ? dist : best1;
        k1    = lt1 ? k    : k1;
        best2 = nb2;
    }

    // outputs (fixup may overwrite flagged tokens)
    const float4* eq = (const float4*)(eT + (size_t)k1 * DD);
    float4* q4 = (float4*)(outQ   + (size_t)n * DD);
    float4* d4 = (float4*)(outDiff + (size_t)n * DD);
#pragma unroll
    for (int i = 0; i < DD / 4; ++i) {
        float4 e4 = eq[i];
        float4 dv;
        float t;
        t = e4.x - x[4 * i + 0]; dv.x = t * t;
        t = e4.y - x[4 * i + 1]; dv.y = t * t;
        t = e4.z - x[4 * i + 2]; dv.z = t * t;
        t = e4.w - x[4 * i + 3]; dv.w = t * t;
        q4[i] = e4;
        d4[i] = dv;
    }
    outInd[n] = (float)k1;
    flags[n] = (best2 - best1 < 0.02f) ? 1 : 0;
}

// One wave per flagged token: exact f64 rescan of all K codes.
__global__ __launch_bounds__(256) void vq_fixup(const float* __restrict__ inp,
                                                const float* __restrict__ eT,
                                                const int* __restrict__ flags,
                                                float* __restrict__ outQ,
                                                float* __restrict__ outDiff,
                                                float* __restrict__ outInd) {
    int waveId = blockIdx.x * 4 + (threadIdx.x >> 6);  // 1024 blocks * 4 waves = 4096
    int lane   = threadIdx.x & 63;

    for (int iter = 0; iter < NN / 4096; ++iter) {
        int n = waveId + iter * 4096;
        if (!flags[n]) continue;                       // wave-uniform branch

        // broadcast-load x row
        float x[DD];
        const float4* xp = (const float4*)(inp + (size_t)n * DD);
#pragma unroll
        for (int i = 0; i < DD / 4; ++i) {
            float4 v = xp[i];
            x[4 * i + 0] = v.x; x[4 * i + 1] = v.y;
            x[4 * i + 2] = v.z; x[4 * i + 3] = v.w;
        }

        double bestd = 1e300;
        int bk = 0;
        for (int c = 0; c < KK / 64; ++c) {
            int k = c * 64 + lane;                     // lane-local codes, k ascending
            const float4* e4 = (const float4*)(eT + (size_t)k * DD);
            double acc = 0.0;
#pragma unroll
            for (int i = 0; i < DD / 4; ++i) {
                float4 ev = e4[i];
                double dx;
                dx = (double)x[4 * i + 0] - (double)ev.x; acc = fma(dx, dx, acc);
                dx = (double)x[4 * i + 1] - (double)ev.y; acc = fma(dx, dx, acc);
                dx = (double)x[4 * i + 2] - (double)ev.z; acc = fma(dx, dx, acc);
                dx = (double)x[4 * i + 3] - (double)ev.w; acc = fma(dx, dx, acc);
            }
            if (acc < bestd) { bestd = acc; bk = k; }  // strict <, k ascending per lane
        }
        // cross-lane argmin, ties -> smaller k (np.argmin first-occurrence)
        for (int off = 32; off > 0; off >>= 1) {
            double od = __shfl_xor(bestd, off);
            int    ok = __shfl_xor(bk, off);
            if (od < bestd || (od == bestd && ok < bk)) { bestd = od; bk = ok; }
        }
        // rewrite this token's outputs (coalesced: one d per lane)
        float q  = eT[(size_t)bk * DD + lane];
        float xv = inp[(size_t)n * DD + lane];
        float dd = q - xv;
        outQ[(size_t)n * DD + lane]    = q;
        outDiff[(size_t)n * DD + lane] = dd * dd;
        if (lane == 0) outInd[n] = (float)bk;
    }
}

extern "C" void kernel_launch(void* const* d_in, const int* in_sizes, int n_in,
                              void* d_out, int out_size, void* d_ws, size_t ws_size,
                              hipStream_t stream) {
    const float* inp   = (const float*)d_in[0];
    const float* embed = (const float*)d_in[1];
    float* outQ    = (float*)d_out;
    float* outDiff = outQ + (size_t)NN * DD;
    float* outInd  = outDiff + (size_t)NN * DD;

    char* ws      = (char*)d_ws;
    float* eT     = (float*)ws;
    float* enorm  = (float*)(ws + 262144);
    int*   flags  = (int*)(ws + 266240);

    vq_prep <<<KK / 256, 256, 0, stream>>>(embed, eT, enorm);
    vq_pass1<<<NN / 256, 256, 0, stream>>>(inp, eT, enorm, outQ, outDiff, outInd, flags);
    vq_fixup<<<1024,     256, 0, stream>>>(inp, eT, flags, outQ, outDiff, outInd);
}

// Round 4
// 241.765 us; speedup vs baseline: 2.3278x; 2.3278x over previous
//
#include <hip/hip_runtime.h>

#define DD 64
#define KK 1024
#define NN 65536   // 16 * 4096 tokens

typedef __attribute__((ext_vector_type(8))) short short8v;  // 8 bf16 = 4 VGPR
typedef __attribute__((ext_vector_type(4))) float f32x4;

// ws layout:
//   [0,      256K) : eT    [K][D] f32   (exact codebook rows, for fixup + epilogue)
//   [256K,   384K) : ehi   [K][D] bf16  (hi part)
//   [384K,   512K) : elo   [K][D] bf16  (lo part: bf16(v - f32(hi)))
//   [512K,   516K) : enorm [K]   f32
//   [516K,   580K) : flags [N]   u8     (1 = near-tie, rescore in f64)

__device__ __forceinline__ unsigned short bf16_rn_bits(float f) {
    unsigned u = __builtin_bit_cast(unsigned, f);
    u += 0x7fffu + ((u >> 16) & 1u);
    return (unsigned short)(u >> 16);
}
__device__ __forceinline__ float bf16_bits_to_f(unsigned short h) {
    return __builtin_bit_cast(float, (unsigned)h << 16);
}

// 16 blocks x 256 threads: block handles 64 codes; thread (kl, dq) covers 16 dims.
__global__ __launch_bounds__(256) void vq_prep(const float* __restrict__ embed,
                                               float* __restrict__ eT,
                                               unsigned short* __restrict__ ehi,
                                               unsigned short* __restrict__ elo,
                                               float* __restrict__ enorm) {
    __shared__ float part[4][64];
    int t  = threadIdx.x;
    int kl = t & 63;
    int dq = t >> 6;
    int k  = blockIdx.x * 64 + kl;
    float s = 0.f;
#pragma unroll
    for (int i = 0; i < 16; ++i) {
        int d = dq * 16 + i;
        float v = embed[d * KK + k];          // coalesced: lanes = consecutive k
        eT[(size_t)k * DD + d] = v;
        unsigned short h = bf16_rn_bits(v);
        float lo = v - bf16_bits_to_f(h);
        ehi[(size_t)k * DD + d] = h;
        elo[(size_t)k * DD + d] = bf16_rn_bits(lo);
        s = fmaf(v, v, s);
    }
    part[dq][kl] = s;
    __syncthreads();
    if (dq == 0) enorm[k] = part[0][kl] + part[1][kl] + part[2][kl] + part[3][kl];
}

// 1024 blocks x 4 waves; wave owns 16 tokens x all K codes via 16x16x32 bf16 MFMA.
__global__ __launch_bounds__(256) void vq_mfma(const float* __restrict__ inp,
                                               const unsigned short* __restrict__ ehi,
                                               const unsigned short* __restrict__ elo,
                                               const float* __restrict__ eT,
                                               const float* __restrict__ enorm,
                                               float* __restrict__ outQ,
                                               float* __restrict__ outDiff,
                                               float* __restrict__ outInd,
                                               unsigned char* __restrict__ flags) {
    int tid  = threadIdx.x;
    int wave = tid >> 6, lane = tid & 63;
    int g = lane >> 4, r = lane & 15;
    int tok0 = blockIdx.x * 64 + wave * 16;

    // A-frags: lane (g,r) holds x[tok0+r][8g+j] for K-halves kh=0 (dims 0-31), kh=1 (32-63)
    short8v a_hi[2], a_lo[2];
    {
        const float* xrow = inp + (size_t)(tok0 + r) * DD + 8 * g;
#pragma unroll
        for (int kh = 0; kh < 2; ++kh) {
            float4 v0 = *(const float4*)(xrow + 32 * kh);
            float4 v1 = *(const float4*)(xrow + 32 * kh + 4);
            float xv[8] = {v0.x, v0.y, v0.z, v0.w, v1.x, v1.y, v1.z, v1.w};
#pragma unroll
            for (int j = 0; j < 8; ++j) {
                unsigned short h = bf16_rn_bits(xv[j]);
                float lo = xv[j] - bf16_bits_to_f(h);
                a_hi[kh][j] = (short)h;
                a_lo[kh][j] = (short)bf16_rn_bits(lo);
            }
        }
    }

    float best1[4], best2[4];
    int k1[4];
#pragma unroll
    for (int j = 0; j < 4; ++j) { best1[j] = 3.4e38f; best2[j] = 3.4e38f; k1[j] = 0; }

#pragma unroll 2
    for (int t = 0; t < KK / 16; ++t) {
        int c = t * 16 + r;                               // this lane's code (B col r)
        const unsigned short* bh = ehi + (size_t)c * DD + 8 * g;
        const unsigned short* bl = elo + (size_t)c * DD + 8 * g;
        short8v bhi0 = *(const short8v*)(bh);
        short8v bhi1 = *(const short8v*)(bh + 32);
        short8v blo0 = *(const short8v*)(bl);
        short8v blo1 = *(const short8v*)(bl + 32);
        float en = enorm[c];

        f32x4 accA = {0.f, 0.f, 0.f, 0.f};               // hi*hi + hi*lo
        f32x4 accB = {0.f, 0.f, 0.f, 0.f};               // lo*hi  (2 indep MFMA chains)
        accA = __builtin_amdgcn_mfma_f32_16x16x32_bf16(a_hi[0], bhi0, accA, 0, 0, 0);
        accB = __builtin_amdgcn_mfma_f32_16x16x32_bf16(a_lo[0], bhi0, accB, 0, 0, 0);
        accA = __builtin_amdgcn_mfma_f32_16x16x32_bf16(a_hi[1], bhi1, accA, 0, 0, 0);
        accB = __builtin_amdgcn_mfma_f32_16x16x32_bf16(a_lo[1], bhi1, accB, 0, 0, 0);
        accA = __builtin_amdgcn_mfma_f32_16x16x32_bf16(a_hi[0], blo0, accA, 0, 0, 0);
        accB = __builtin_amdgcn_mfma_f32_16x16x32_bf16(a_hi[1], blo1, accB, 0, 0, 0);

#pragma unroll
        for (int j = 0; j < 4; ++j) {                    // C row = 4g+j -> token tok0+4g+j
            float dist = fmaf(-2.f, accA[j] + accB[j], en);
            bool lt1 = dist < best1[j];                  // strict <, c ascending per lane
            bool lt2 = dist < best2[j];
            float nb2 = lt1 ? best1[j] : (lt2 ? dist : best2[j]);
            best1[j] = lt1 ? dist : best1[j];
            k1[j]    = lt1 ? c    : k1[j];
            best2[j] = nb2;
        }
    }

    // merge cols across the 16 lanes of each group (masks stay within group)
#pragma unroll
    for (int m = 1; m < 16; m <<= 1) {
#pragma unroll
        for (int j = 0; j < 4; ++j) {
            float ob1 = __shfl_xor(best1[j], m, 64);
            float ob2 = __shfl_xor(best2[j], m, 64);
            int   ok  = __shfl_xor(k1[j],   m, 64);
            bool takeOther = (ob1 < best1[j]) || (ob1 == best1[j] && ok < k1[j]);
            float lose = takeOther ? best1[j] : ob1;     // losing best1 joins 2nd-best pool
            best1[j] = takeOther ? ob1 : best1[j];
            k1[j]    = takeOther ? ok  : k1[j];
            best2[j] = fminf(fminf(best2[j], ob2), lose);
        }
    }

    if (r == 0) {
#pragma unroll
        for (int j = 0; j < 4; ++j) {
            int tok = tok0 + 4 * g + j;
            outInd[tok] = (float)k1[j];
            flags[tok]  = (best2[j] - best1[j] < 0.02f) ? 1 : 0;
        }
    }

    // epilogue: whole wave writes 16 token rows (256B coalesced per row)
#pragma unroll
    for (int tt = 0; tt < 16; ++tt) {
        int k = __shfl(k1[tt & 3], (tt >> 2) * 16, 64);
        float ev = eT[(size_t)k * DD + lane];
        float xv = inp[(size_t)(tok0 + tt) * DD + lane];
        float d  = ev - xv;
        outQ[(size_t)(tok0 + tt) * DD + lane]    = ev;
        outDiff[(size_t)(tok0 + tt) * DD + lane] = d * d;
    }
}

// One wave per flagged token: exact f64 rescan of all K codes (np-argmin semantics).
__global__ __launch_bounds__(256) void vq_fixup(const float* __restrict__ inp,
                                                const float* __restrict__ eT,
                                                const unsigned char* __restrict__ flags,
                                                float* __restrict__ outQ,
                                                float* __restrict__ outDiff,
                                                float* __restrict__ outInd) {
    int waveId = blockIdx.x * 4 + (threadIdx.x >> 6);
    int lane   = threadIdx.x & 63;

    for (int iter = 0; iter < NN / 4096; ++iter) {
        int n = waveId + iter * 4096;
        if (!flags[n]) continue;                       // wave-uniform branch

        float x[DD];
        const float4* xp = (const float4*)(inp + (size_t)n * DD);
#pragma unroll
        for (int i = 0; i < DD / 4; ++i) {
            float4 v = xp[i];
            x[4 * i + 0] = v.x; x[4 * i + 1] = v.y;
            x[4 * i + 2] = v.z; x[4 * i + 3] = v.w;
        }

        double bestd = 1e300;
        int bk = 0;
        for (int c = 0; c < KK / 64; ++c) {
            int k = c * 64 + lane;
            const float4* e4 = (const float4*)(eT + (size_t)k * DD);
            double acc = 0.0;
#pragma unroll
            for (int i = 0; i < DD / 4; ++i) {
                float4 ev = e4[i];
                double dx;
                dx = (double)x[4 * i + 0] - (double)ev.x; acc = fma(dx, dx, acc);
                dx = (double)x[4 * i + 1] - (double)ev.y; acc = fma(dx, dx, acc);
                dx = (double)x[4 * i + 2] - (double)ev.z; acc = fma(dx, dx, acc);
                dx = (double)x[4 * i + 3] - (double)ev.w; acc = fma(dx, dx, acc);
            }
            if (acc < bestd) { bestd = acc; bk = k; }
        }
        for (int off = 32; off > 0; off >>= 1) {
            double od = __shfl_xor(bestd, off);
            int    ok = __shfl_xor(bk, off);
            if (od < bestd || (od == bestd && ok < bk)) { bestd = od; bk = ok; }
        }
        float q  = eT[(size_t)bk * DD + lane];
        float xv = inp[(size_t)n * DD + lane];
        float dd = q - xv;
        outQ[(size_t)n * DD + lane]    = q;
        outDiff[(size_t)n * DD + lane] = dd * dd;
        if (lane == 0) outInd[n] = (float)bk;
    }
}

extern "C" void kernel_launch(void* const* d_in, const int* in_sizes, int n_in,
                              void* d_out, int out_size, void* d_ws, size_t ws_size,
                              hipStream_t stream) {
    const float* inp   = (const float*)d_in[0];
    const float* embed = (const float*)d_in[1];
    float* outQ    = (float*)d_out;
    float* outDiff = outQ + (size_t)NN * DD;
    float* outInd  = outDiff + (size_t)NN * DD;

    char* ws = (char*)d_ws;
    float*          eT    = (float*)(ws);
    unsigned short* ehi   = (unsigned short*)(ws + 262144);
    unsigned short* elo   = (unsigned short*)(ws + 393216);
    float*          enorm = (float*)(ws + 524288);
    unsigned char*  flags = (unsigned char*)(ws + 528384);

    vq_prep <<<16,   256, 0, stream>>>(embed, eT, ehi, elo, enorm);
    vq_mfma <<<1024, 256, 0, stream>>>(inp, ehi, elo, eT, enorm, outQ, outDiff, outInd, flags);
    vq_fixup<<<1024, 256, 0, stream>>>(inp, eT, flags, outQ, outDiff, outInd);
}

// Round 9
// 187.730 us; speedup vs baseline: 2.9978x; 1.2878x over previous
//
#include <hip/hip_runtime.h>

#define DD 64
#define KK 1024
#define NN 65536   // 16 * 4096 tokens

typedef __attribute__((ext_vector_type(8))) short short8v;  // 8 bf16 = 4 VGPR
typedef __attribute__((ext_vector_type(4))) float f32x4;

// ws layout:
//   [0,      256K) : eT    [K][D] f32   (exact codebook rows, for fixup + epilogue)
//   [256K,   384K) : ehi   [K][D] bf16  (hi part)
//   [384K,   512K) : elo   [K][D] bf16  (lo part: bf16(v - f32(hi)))
//   [512K,   516K) : enorm [K]   f32
//   [516K,   580K) : flags [N]   u8     (1 = near-tie, rescore in f64)

__device__ __forceinline__ unsigned short bf16_rn_bits(float f) {
    unsigned u = __builtin_bit_cast(unsigned, f);
    u += 0x7fffu + ((u >> 16) & 1u);
    return (unsigned short)(u >> 16);
}
__device__ __forceinline__ float bf16_bits_to_f(unsigned short h) {
    return __builtin_bit_cast(float, (unsigned)h << 16);
}

__global__ __launch_bounds__(256) void vq_prep(const float* __restrict__ embed,
                                               float* __restrict__ eT,
                                               unsigned short* __restrict__ ehi,
                                               unsigned short* __restrict__ elo,
                                               float* __restrict__ enorm) {
    __shared__ float part[4][64];
    int t  = threadIdx.x;
    int kl = t & 63;
    int dq = t >> 6;
    int k  = blockIdx.x * 64 + kl;
    float s = 0.f;
#pragma unroll
    for (int i = 0; i < 16; ++i) {
        int d = dq * 16 + i;
        float v = embed[d * KK + k];          // coalesced: lanes = consecutive k
        eT[(size_t)k * DD + d] = v;
        unsigned short h = bf16_rn_bits(v);
        float lo = v - bf16_bits_to_f(h);
        ehi[(size_t)k * DD + d] = h;
        elo[(size_t)k * DD + d] = bf16_rn_bits(lo);
        s = fmaf(v, v, s);
    }
    part[dq][kl] = s;
    __syncthreads();
    if (dq == 0) enorm[k] = part[0][kl] + part[1][kl] + part[2][kl] + part[3][kl];
}

// 1024 blocks x 4 waves. Block = 64 tokens. Wave (mg,kh): 32 tokens (2 M-tiles) x 512 codes.
__global__ __launch_bounds__(256) void vq_mfma(const float* __restrict__ inp,
                                               const unsigned short* __restrict__ ehi,
                                               const unsigned short* __restrict__ elo,
                                               const float* __restrict__ eT,
                                               const float* __restrict__ enorm,
                                               float* __restrict__ outQ,
                                               float* __restrict__ outDiff,
                                               float* __restrict__ outInd,
                                               unsigned char* __restrict__ flags) {
    __shared__ float s_b1[64][2];
    __shared__ float s_b2[64][2];
    __shared__ int   s_k1[64][2];
    __shared__ int   s_kwin[64];

    int tid  = threadIdx.x;
    int wave = tid >> 6, lane = tid & 63;
    int g = lane >> 4, r = lane & 15;
    int mg = wave >> 1, kh = wave & 1;
    int tokBlk = blockIdx.x * 64;
    int tok0   = tokBlk + mg * 32;            // this wave's 32 tokens

    // A-frags: [m-tile][D-half]; lane (g,r) holds x[tok0+16m+r][8g..8g+8) per D-half
    short8v a_hi[2][2], a_lo[2][2];
#pragma unroll
    for (int m = 0; m < 2; ++m) {
        const float* xrow = inp + (size_t)(tok0 + 16 * m + r) * DD + 8 * g;
#pragma unroll
        for (int dh = 0; dh < 2; ++dh) {
            float4 v0 = *(const float4*)(xrow + 32 * dh);
            float4 v1 = *(const float4*)(xrow + 32 * dh + 4);
            float xv[8] = {v0.x, v0.y, v0.z, v0.w, v1.x, v1.y, v1.z, v1.w};
#pragma unroll
            for (int j = 0; j < 8; ++j) {
                unsigned short h = bf16_rn_bits(xv[j]);
                float lo = xv[j] - bf16_bits_to_f(h);
                a_hi[m][dh][j] = (short)h;
                a_lo[m][dh][j] = (short)bf16_rn_bits(lo);
            }
        }
    }

    float best1[2][4], best2[2][4];
    int k1[2][4];
#pragma unroll
    for (int m = 0; m < 2; ++m)
#pragma unroll
        for (int j = 0; j < 4; ++j) { best1[m][j] = 3.4e38f; best2[m][j] = 3.4e38f; k1[m][j] = 0; }

#pragma unroll 2
    for (int t = 0; t < KK / 32; ++t) {       // 32 iterations over this wave's K-half
        int c = kh * 512 + t * 16 + r;        // this lane's code (B col r)
        const unsigned short* bh = ehi + (size_t)c * DD + 8 * g;
        const unsigned short* bl = elo + (size_t)c * DD + 8 * g;
        short8v bhi0 = *(const short8v*)(bh);
        short8v bhi1 = *(const short8v*)(bh + 32);
        short8v blo0 = *(const short8v*)(bl);
        short8v blo1 = *(const short8v*)(bl + 32);
        float en = enorm[c];

        f32x4 accA0 = {0.f,0.f,0.f,0.f}, accA1 = {0.f,0.f,0.f,0.f};
        f32x4 accB0 = {0.f,0.f,0.f,0.f}, accB1 = {0.f,0.f,0.f,0.f};
        // 12 MFMAs, 4 independent chains interleaved (hi*hi + hi*lo + lo*hi)
        accA0 = __builtin_amdgcn_mfma_f32_16x16x32_bf16(a_hi[0][0], bhi0, accA0, 0, 0, 0);
        accA1 = __builtin_amdgcn_mfma_f32_16x16x32_bf16(a_hi[1][0], bhi0, accA1, 0, 0, 0);
        accB0 = __builtin_amdgcn_mfma_f32_16x16x32_bf16(a_lo[0][0], bhi0, accB0, 0, 0, 0);
        accB1 = __builtin_amdgcn_mfma_f32_16x16x32_bf16(a_lo[1][0], bhi0, accB1, 0, 0, 0);
        accA0 = __builtin_amdgcn_mfma_f32_16x16x32_bf16(a_hi[0][1], bhi1, accA0, 0, 0, 0);
        accA1 = __builtin_amdgcn_mfma_f32_16x16x32_bf16(a_hi[1][1], bhi1, accA1, 0, 0, 0);
        accB0 = __builtin_amdgcn_mfma_f32_16x16x32_bf16(a_lo[0][1], bhi1, accB0, 0, 0, 0);
        accB1 = __builtin_amdgcn_mfma_f32_16x16x32_bf16(a_lo[1][1], bhi1, accB1, 0, 0, 0);
        accA0 = __builtin_amdgcn_mfma_f32_16x16x32_bf16(a_hi[0][0], blo0, accA0, 0, 0, 0);
        accA1 = __builtin_amdgcn_mfma_f32_16x16x32_bf16(a_hi[1][0], blo0, accA1, 0, 0, 0);
        accA0 = __builtin_amdgcn_mfma_f32_16x16x32_bf16(a_hi[0][1], blo1, accA0, 0, 0, 0);
        accA1 = __builtin_amdgcn_mfma_f32_16x16x32_bf16(a_hi[1][1], blo1, accA1, 0, 0, 0);

#pragma unroll
        for (int m = 0; m < 2; ++m) {
            const f32x4& aA = m ? accA1 : accA0;
            const f32x4& aB = m ? accB1 : accB0;
#pragma unroll
            for (int j = 0; j < 4; ++j) {     // C row = 4g+j -> token tok0+16m+4g+j
                float dist = fmaf(-2.f, aA[j] + aB[j], en);
                bool lt1 = dist < best1[m][j];
                bool lt2 = dist < best2[m][j];
                float nb2 = lt1 ? best1[m][j] : (lt2 ? dist : best2[m][j]);
                best1[m][j] = lt1 ? dist : best1[m][j];
                k1[m][j]    = lt1 ? c    : k1[m][j];
                best2[m][j] = nb2;
            }
        }
    }

    // merge across the 16 lanes of each group (xor masks < 16 stay in-group)
#pragma unroll
    for (int msk = 1; msk < 16; msk <<= 1) {
#pragma unroll
        for (int m = 0; m < 2; ++m)
#pragma unroll
            for (int j = 0; j < 4; ++j) {
                float ob1 = __shfl_xor(best1[m][j], msk, 64);
                float ob2 = __shfl_xor(best2[m][j], msk, 64);
                int   ok  = __shfl_xor(k1[m][j],   msk, 64);
                bool takeOther = (ob1 < best1[m][j]) || (ob1 == best1[m][j] && ok < k1[m][j]);
                float lose = takeOther ? best1[m][j] : ob1;
                best1[m][j] = takeOther ? ob1 : best1[m][j];
                k1[m][j]    = takeOther ? ok  : k1[m][j];
                best2[m][j] = fminf(fminf(best2[m][j], ob2), lose);
            }
    }

    if (r == 0) {
#pragma unroll
        for (int m = 0; m < 2; ++m)
#pragma unroll
            for (int j = 0; j < 4; ++j) {
                int tl = mg * 32 + m * 16 + 4 * g + j;    // token within block
                s_b1[tl][kh] = best1[m][j];
                s_b2[tl][kh] = best2[m][j];
                s_k1[tl][kh] = k1[m][j];
            }
    }
    __syncthreads();

    // threads 0..63: merge the two K-halves for token tid (half 0 has lower k: ties -> half 0)
    if (tid < 64) {
        float b1a = s_b1[tid][0], b2a = s_b2[tid][0];
        float b1b = s_b1[tid][1], b2b = s_b2[tid][1];
        int   ka  = s_k1[tid][0], kb  = s_k1[tid][1];
        float nb1, nb2; int nk;
        if (b1b < b1a) { nb1 = b1b; nk = kb; nb2 = fminf(b1a, b2b); }
        else           { nb1 = b1a; nk = ka; nb2 = fminf(b2a, b1b); }
        int tok = tokBlk + tid;
        outInd[tok]  = (float)nk;
        flags[tok]   = (nb2 - nb1 < 0.02f) ? 1 : 0;
        s_kwin[tid]  = nk;
    }
    __syncthreads();

    // epilogue: wave w writes block-tokens [16w, 16w+16), one 256B row per step
#pragma unroll
    for (int tt = 0; tt < 16; ++tt) {
        int tl = wave * 16 + tt;
        int k  = s_kwin[tl];                               // uniform LDS broadcast
        float ev = eT[(size_t)k * DD + lane];
        float xv = inp[(size_t)(tokBlk + tl) * DD + lane];
        float d  = ev - xv;
        outQ[(size_t)(tokBlk + tl) * DD + lane]    = ev;
        outDiff[(size_t)(tokBlk + tl) * DD + lane] = d * d;
    }
}

// One wave per flagged token: exact f64 rescan of all K codes (np-argmin semantics).
__global__ __launch_bounds__(256) void vq_fixup(const float* __restrict__ inp,
                                                const float* __restrict__ eT,
                                                const unsigned char* __restrict__ flags,
                                                float* __restrict__ outQ,
                                                float* __restrict__ outDiff,
                                                float* __restrict__ outInd) {
    int waveId = blockIdx.x * 4 + (threadIdx.x >> 6);
    int lane   = threadIdx.x & 63;

    for (int iter = 0; iter < NN / 4096; ++iter) {
        int n = waveId + iter * 4096;
        if (!flags[n]) continue;                       // wave-uniform branch

        float x[DD];
        const float4* xp = (const float4*)(inp + (size_t)n * DD);
#pragma unroll
        for (int i = 0; i < DD / 4; ++i) {
            float4 v = xp[i];
            x[4 * i + 0] = v.x; x[4 * i + 1] = v.y;
            x[4 * i + 2] = v.z; x[4 * i + 3] = v.w;
        }

        double bestd = 1e300;
        int bk = 0;
        for (int c = 0; c < KK / 64; ++c) {
            int k = c * 64 + lane;
            const float4* e4 = (const float4*)(eT + (size_t)k * DD);
            double acc = 0.0;
#pragma unroll
            for (int i = 0; i < DD / 4; ++i) {
                float4 ev = e4[i];
                double dx;
                dx = (double)x[4 * i + 0] - (double)ev.x; acc = fma(dx, dx, acc);
                dx = (double)x[4 * i + 1] - (double)ev.y; acc = fma(dx, dx, acc);
                dx = (double)x[4 * i + 2] - (double)ev.z; acc = fma(dx, dx, acc);
                dx = (double)x[4 * i + 3] - (double)ev.w; acc = fma(dx, dx, acc);
            }
            if (acc < bestd) { bestd = acc; bk = k; }
        }
        for (int off = 32; off > 0; off >>= 1) {
            double od = __shfl_xor(bestd, off);
            int    ok = __shfl_xor(bk, off);
            if (od < bestd || (od == bestd && ok < bk)) { bestd = od; bk = ok; }
        }
        float q  = eT[(size_t)bk * DD + lane];
        float xv = inp[(size_t)n * DD + lane];
        float dd = q - xv;
        outQ[(size_t)n * DD + lane]    = q;
        outDiff[(size_t)n * DD + lane] = dd * dd;
        if (lane == 0) outInd[n] = (float)bk;
    }
}

extern "C" void kernel_launch(void* const* d_in, const int* in_sizes, int n_in,
                              void* d_out, int out_size, void* d_ws, size_t ws_size,
                              hipStream_t stream) {
    const float* inp   = (const float*)d_in[0];
    const float* embed = (const float*)d_in[1];
    float* outQ    = (float*)d_out;
    float* outDiff = outQ + (size_t)NN * DD;
    float* outInd  = outDiff + (size_t)NN * DD;

    char* ws = (char*)d_ws;
    float*          eT    = (float*)(ws);
    unsigned short* ehi   = (unsigned short*)(ws + 262144);
    unsigned short* elo   = (unsigned short*)(ws + 393216);
    float*          enorm = (float*)(ws + 524288);
    unsigned char*  flags = (unsigned char*)(ws + 528384);

    vq_prep <<<16,   256, 0, stream>>>(embed, eT, ehi, elo, enorm);
    vq_mfma <<<1024, 256, 0, stream>>>(inp, ehi, elo, eT, enorm, outQ, outDiff, outInd, flags);
    vq_fixup<<<1024, 256, 0, stream>>>(inp, eT, flags, outQ, outDiff, outInd);
}

// Round 11
// 156.724 us; speedup vs baseline: 3.5909x; 1.1978x over previous
//
#include <hip/hip_runtime.h>

#define DD 64
#define KK 1024
#define NN 65536   // 16 * 4096 tokens

typedef __attribute__((ext_vector_type(8))) short short8v;  // 8 bf16 = 4 VGPR
typedef __attribute__((ext_vector_type(4))) float f32x4;

// ws layout:
//   [0,      256K) : eT   [K][D] f32      (exact codebook rows: fixup + epilogue)
//   [256K,   384K) : ehp  packed bf16 hi  [tile][dh][lane][8]  (fragment order)
//   [384K,   512K) : elp  packed bf16 lo  [tile][dh][lane][8]
//   [512K,   516K) : enorm [K] f32
//   [516K,   580K) : flags [N] u8         (1 = near-tie, rescore in f64)
//
// Packed layout: for code c, dim d:
//   tile=c>>4, r=c&15, dh=d>>5, g=(d&31)>>3, j=d&7
//   ehp[(((tile*2+dh)*64) + g*16 + r)*8 + j]
// so a wave's B-frag load for tile tg is the contiguous 1KB at (tg*2+dh)*64*8,
// lane l reading 16B at offset l*16  -> fully coalesced (was 16x128B-strided).

__device__ __forceinline__ unsigned short bf16_rn_bits(float f) {
    unsigned u = __builtin_bit_cast(unsigned, f);
    u += 0x7fffu + ((u >> 16) & 1u);
    return (unsigned short)(u >> 16);
}
__device__ __forceinline__ float bf16_bits_to_f(unsigned short h) {
    return __builtin_bit_cast(float, (unsigned)h << 16);
}

__global__ __launch_bounds__(256) void vq_prep(const float* __restrict__ embed,
                                               float* __restrict__ eT,
                                               unsigned short* __restrict__ ehp,
                                               unsigned short* __restrict__ elp,
                                               float* __restrict__ enorm) {
    __shared__ float part[4][64];
    int t  = threadIdx.x;
    int kl = t & 63;
    int dq = t >> 6;
    int k  = blockIdx.x * 64 + kl;
    int tile = k >> 4, r = k & 15;
    float s = 0.f;
#pragma unroll
    for (int i = 0; i < 16; ++i) {
        int d = dq * 16 + i;
        float v = embed[d * KK + k];          // coalesced: lanes = consecutive k
        eT[(size_t)k * DD + d] = v;
        unsigned short h = bf16_rn_bits(v);
        float lo = v - bf16_bits_to_f(h);
        int dh = d >> 5, g = (d & 31) >> 3, j = d & 7;
        size_t idx = ((size_t)((tile * 2 + dh) * 64 + g * 16 + r)) * 8 + j;
        ehp[idx] = h;
        elp[idx] = bf16_rn_bits(lo);
        s = fmaf(v, v, s);
    }
    part[dq][kl] = s;
    __syncthreads();
    if (dq == 0) enorm[k] = part[0][kl] + part[1][kl] + part[2][kl] + part[3][kl];
}

// 1024 blocks x 4 waves. Block = 64 tokens. Wave (mg,kh): 32 tokens (2 M-tiles) x 512 codes.
__global__ __launch_bounds__(256) void vq_mfma(const float* __restrict__ inp,
                                               const unsigned short* __restrict__ ehp,
                                               const unsigned short* __restrict__ elp,
                                               const float* __restrict__ eT,
                                               const float* __restrict__ enorm,
                                               float* __restrict__ outQ,
                                               float* __restrict__ outDiff,
                                               float* __restrict__ outInd,
                                               unsigned char* __restrict__ flags) {
    __shared__ float s_b1[64][2];
    __shared__ float s_b2[64][2];
    __shared__ int   s_k1[64][2];
    __shared__ int   s_kwin[64];

    int tid  = threadIdx.x;
    int wave = tid >> 6, lane = tid & 63;
    int g = lane >> 4, r = lane & 15;
    int mg = wave >> 1, kh = wave & 1;
    int tokBlk = blockIdx.x * 64;
    int tok0   = tokBlk + mg * 32;            // this wave's 32 tokens

    // A-frags: [m-tile][D-half]; lane (g,r) holds x[tok0+16m+r][32dh+8g..+8)
    short8v a_hi[2][2], a_lo[2][2];
#pragma unroll
    for (int m = 0; m < 2; ++m) {
        const float* xrow = inp + (size_t)(tok0 + 16 * m + r) * DD + 8 * g;
#pragma unroll
        for (int dh = 0; dh < 2; ++dh) {
            float4 v0 = *(const float4*)(xrow + 32 * dh);
            float4 v1 = *(const float4*)(xrow + 32 * dh + 4);
            float xv[8] = {v0.x, v0.y, v0.z, v0.w, v1.x, v1.y, v1.z, v1.w};
#pragma unroll
            for (int j = 0; j < 8; ++j) {
                unsigned short h = bf16_rn_bits(xv[j]);
                float lo = xv[j] - bf16_bits_to_f(h);
                a_hi[m][dh][j] = (short)h;
                a_lo[m][dh][j] = (short)bf16_rn_bits(lo);
            }
        }
    }

    float best1[2][4], best2[2][4];
    int k1[2][4];
#pragma unroll
    for (int m = 0; m < 2; ++m)
#pragma unroll
        for (int j = 0; j < 4; ++j) { best1[m][j] = 3.4e38f; best2[m][j] = 3.4e38f; k1[m][j] = 0; }

    const short8v* hp = (const short8v*)ehp;   // [tile*2+dh][lane] of 16B frags
    const short8v* lp = (const short8v*)elp;

#pragma unroll 2
    for (int t = 0; t < KK / 32; ++t) {       // 32 iterations over this wave's K-half
        int tg = kh * 32 + t;                 // global 16-code tile
        int c  = tg * 16 + r;                 // this lane's code (B col r)
        short8v bhi0 = hp[(tg * 2 + 0) * 64 + lane];   // coalesced 1KB/wave
        short8v bhi1 = hp[(tg * 2 + 1) * 64 + lane];
        short8v blo0 = lp[(tg * 2 + 0) * 64 + lane];
        short8v blo1 = lp[(tg * 2 + 1) * 64 + lane];
        float en = enorm[c];

        f32x4 accA0 = {0.f,0.f,0.f,0.f}, accA1 = {0.f,0.f,0.f,0.f};
        f32x4 accB0 = {0.f,0.f,0.f,0.f}, accB1 = {0.f,0.f,0.f,0.f};
        // 12 MFMAs, 4 independent chains interleaved (hi*hi + hi*lo + lo*hi)
        accA0 = __builtin_amdgcn_mfma_f32_16x16x32_bf16(a_hi[0][0], bhi0, accA0, 0, 0, 0);
        accA1 = __builtin_amdgcn_mfma_f32_16x16x32_bf16(a_hi[1][0], bhi0, accA1, 0, 0, 0);
        accB0 = __builtin_amdgcn_mfma_f32_16x16x32_bf16(a_lo[0][0], bhi0, accB0, 0, 0, 0);
        accB1 = __builtin_amdgcn_mfma_f32_16x16x32_bf16(a_lo[1][0], bhi0, accB1, 0, 0, 0);
        accA0 = __builtin_amdgcn_mfma_f32_16x16x32_bf16(a_hi[0][1], bhi1, accA0, 0, 0, 0);
        accA1 = __builtin_amdgcn_mfma_f32_16x16x32_bf16(a_hi[1][1], bhi1, accA1, 0, 0, 0);
        accB0 = __builtin_amdgcn_mfma_f32_16x16x32_bf16(a_lo[0][1], bhi1, accB0, 0, 0, 0);
        accB1 = __builtin_amdgcn_mfma_f32_16x16x32_bf16(a_lo[1][1], bhi1, accB1, 0, 0, 0);
        accA0 = __builtin_amdgcn_mfma_f32_16x16x32_bf16(a_hi[0][0], blo0, accA0, 0, 0, 0);
        accA1 = __builtin_amdgcn_mfma_f32_16x16x32_bf16(a_hi[1][0], blo0, accA1, 0, 0, 0);
        accA0 = __builtin_amdgcn_mfma_f32_16x16x32_bf16(a_hi[0][1], blo1, accA0, 0, 0, 0);
        accA1 = __builtin_amdgcn_mfma_f32_16x16x32_bf16(a_hi[1][1], blo1, accA1, 0, 0, 0);

#pragma unroll
        for (int m = 0; m < 2; ++m) {
            const f32x4& aA = m ? accA1 : accA0;
            const f32x4& aB = m ? accB1 : accB0;
#pragma unroll
            for (int j = 0; j < 4; ++j) {     // C row = 4g+j -> token tok0+16m+4g+j
                float dist = fmaf(-2.f, aA[j] + aB[j], en);
                bool lt1 = dist < best1[m][j];
                bool lt2 = dist < best2[m][j];
                float nb2 = lt1 ? best1[m][j] : (lt2 ? dist : best2[m][j]);
                best1[m][j] = lt1 ? dist : best1[m][j];
                k1[m][j]    = lt1 ? c    : k1[m][j];
                best2[m][j] = nb2;
            }
        }
    }

    // merge across the 16 lanes of each group (xor masks < 16 stay in-group)
#pragma unroll
    for (int msk = 1; msk < 16; msk <<= 1) {
#pragma unroll
        for (int m = 0; m < 2; ++m)
#pragma unroll
            for (int j = 0; j < 4; ++j) {
                float ob1 = __shfl_xor(best1[m][j], msk, 64);
                float ob2 = __shfl_xor(best2[m][j], msk, 64);
                int   ok  = __shfl_xor(k1[m][j],   msk, 64);
                bool takeOther = (ob1 < best1[m][j]) || (ob1 == best1[m][j] && ok < k1[m][j]);
                float lose = takeOther ? best1[m][j] : ob1;
                best1[m][j] = takeOther ? ob1 : best1[m][j];
                k1[m][j]    = takeOther ? ok  : k1[m][j];
                best2[m][j] = fminf(fminf(best2[m][j], ob2), lose);
            }
    }

    if (r == 0) {
#pragma unroll
        for (int m = 0; m < 2; ++m)
#pragma unroll
            for (int j = 0; j < 4; ++j) {
                int tl = mg * 32 + m * 16 + 4 * g + j;    // token within block
                s_b1[tl][kh] = best1[m][j];
                s_b2[tl][kh] = best2[m][j];
                s_k1[tl][kh] = k1[m][j];
            }
    }
    __syncthreads();

    // threads 0..63: merge the two K-halves for token tid (half 0 has lower k: ties -> half 0)
    if (tid < 64) {
        float b1a = s_b1[tid][0], b2a = s_b2[tid][0];
        float b1b = s_b1[tid][1], b2b = s_b2[tid][1];
        int   ka  = s_k1[tid][0], kb  = s_k1[tid][1];
        float nb1, nb2; int nk;
        if (b1b < b1a) { nb1 = b1b; nk = kb; nb2 = fminf(b1a, b2b); }
        else           { nb1 = b1a; nk = ka; nb2 = fminf(b2a, b1b); }
        int tok = tokBlk + tid;
        outInd[tok]  = (float)nk;
        flags[tok]   = (nb2 - nb1 < 0.02f) ? 1 : 0;
        s_kwin[tid]  = nk;
    }
    __syncthreads();

    // epilogue: wave w writes block-tokens [16w, 16w+16), one 256B row per step
#pragma unroll
    for (int tt = 0; tt < 16; ++tt) {
        int tl = wave * 16 + tt;
        int k  = s_kwin[tl];                               // uniform LDS broadcast
        float ev = eT[(size_t)k * DD + lane];
        float xv = inp[(size_t)(tokBlk + tl) * DD + lane];
        float d  = ev - xv;
        outQ[(size_t)(tokBlk + tl) * DD + lane]    = ev;
        outDiff[(size_t)(tokBlk + tl) * DD + lane] = d * d;
    }
}

// One wave per flagged token: exact f64 rescan of all K codes (np-argmin semantics).
__global__ __launch_bounds__(256) void vq_fixup(const float* __restrict__ inp,
                                                const float* __restrict__ eT,
                                                const unsigned char* __restrict__ flags,
                                                float* __restrict__ outQ,
                                                float* __restrict__ outDiff,
                                                float* __restrict__ outInd) {
    int waveId = blockIdx.x * 4 + (threadIdx.x >> 6);
    int lane   = threadIdx.x & 63;

    for (int iter = 0; iter < NN / 4096; ++iter) {
        int n = waveId + iter * 4096;
        if (!flags[n]) continue;                       // wave-uniform branch

        float x[DD];
        const float4* xp = (const float4*)(inp + (size_t)n * DD);
#pragma unroll
        for (int i = 0; i < DD / 4; ++i) {
            float4 v = xp[i];
            x[4 * i + 0] = v.x; x[4 * i + 1] = v.y;
            x[4 * i + 2] = v.z; x[4 * i + 3] = v.w;
        }

        double bestd = 1e300;
        int bk = 0;
        for (int c = 0; c < KK / 64; ++c) {
            int k = c * 64 + lane;
            const float4* e4 = (const float4*)(eT + (size_t)k * DD);
            double acc = 0.0;
#pragma unroll
            for (int i = 0; i < DD / 4; ++i) {
                float4 ev = e4[i];
                double dx;
                dx = (double)x[4 * i + 0] - (double)ev.x; acc = fma(dx, dx, acc);
                dx = (double)x[4 * i + 1] - (double)ev.y; acc = fma(dx, dx, acc);
                dx = (double)x[4 * i + 2] - (double)ev.z; acc = fma(dx, dx, acc);
                dx = (double)x[4 * i + 3] - (double)ev.w; acc = fma(dx, dx, acc);
            }
            if (acc < bestd) { bestd = acc; bk = k; }
        }
        for (int off = 32; off > 0; off >>= 1) {
            double od = __shfl_xor(bestd, off);
            int    ok = __shfl_xor(bk, off);
            if (od < bestd || (od == bestd && ok < bk)) { bestd = od; bk = ok; }
        }
        float q  = eT[(size_t)bk * DD + lane];
        float xv = inp[(size_t)n * DD + lane];
        float dd = q - xv;
        outQ[(size_t)n * DD + lane]    = q;
        outDiff[(size_t)n * DD + lane] = dd * dd;
        if (lane == 0) outInd[n] = (float)bk;
    }
}

extern "C" void kernel_launch(void* const* d_in, const int* in_sizes, int n_in,
                              void* d_out, int out_size, void* d_ws, size_t ws_size,
                              hipStream_t stream) {
    const float* inp   = (const float*)d_in[0];
    const float* embed = (const float*)d_in[1];
    float* outQ    = (float*)d_out;
    float* outDiff = outQ + (size_t)NN * DD;
    float* outInd  = outDiff + (size_t)NN * DD;

    char* ws = (char*)d_ws;
    float*          eT    = (float*)(ws);
    unsigned short* ehp   = (unsigned short*)(ws + 262144);
    unsigned short* elp   = (unsigned short*)(ws + 393216);
    float*          enorm = (float*)(ws + 524288);
    unsigned char*  flags = (unsigned char*)(ws + 528384);

    vq_prep <<<16,   256, 0, stream>>>(embed, eT, ehp, elp, enorm);
    vq_mfma <<<1024, 256, 0, stream>>>(inp, ehp, elp, eT, enorm, outQ, outDiff, outInd, flags);
    vq_fixup<<<1024, 256, 0, stream>>>(inp, eT, flags, outQ, outDiff, outInd);
}

// Round 13
// 129.415 us; speedup vs baseline: 4.3487x; 1.2110x over previous
//
#include <hip/hip_runtime.h>

#define DD 64
#define KK 1024
#define NN 65536    // 16 * 4096 tokens
#define FCAP 16384  // fixup list capacity (observed ~290 flagged)

typedef __attribute__((ext_vector_type(8))) short short8v;  // 8 bf16 = 4 VGPR
typedef __attribute__((ext_vector_type(4))) float f32x4;

// ws layout:
//   [0,      256K) : eT   [K][D] f32      (exact codebook rows: fixup + epilogue)
//   [256K,   384K) : ehp  packed bf16 hi  [tile][dh][lane][8]  (fragment order)
//   [384K,   512K) : elp  packed bf16 lo  [tile][dh][lane][8]
//   [512K,   516K) : enorm [K] f32
//   [516K,  +16B ) : fcount (int)         (# near-tie tokens)
//   [516K+16, +64K): flist  (int[FCAP])   (near-tie token ids)

__device__ __forceinline__ unsigned short bf16_rn_bits(float f) {
    unsigned u = __builtin_bit_cast(unsigned, f);
    u += 0x7fffu + ((u >> 16) & 1u);
    return (unsigned short)(u >> 16);
}
__device__ __forceinline__ float bf16_bits_to_f(unsigned short h) {
    return __builtin_bit_cast(float, (unsigned)h << 16);
}

__global__ __launch_bounds__(256) void vq_prep(const float* __restrict__ embed,
                                               float* __restrict__ eT,
                                               unsigned short* __restrict__ ehp,
                                               unsigned short* __restrict__ elp,
                                               float* __restrict__ enorm,
                                               int* __restrict__ fcount) {
    if (blockIdx.x == 0 && threadIdx.x == 0) *fcount = 0;   // before vq_mfma (stream order)
    __shared__ float part[4][64];
    int t  = threadIdx.x;
    int kl = t & 63;
    int dq = t >> 6;
    int k  = blockIdx.x * 64 + kl;
    int tile = k >> 4, r = k & 15;
    float s = 0.f;
#pragma unroll
    for (int i = 0; i < 16; ++i) {
        int d = dq * 16 + i;
        float v = embed[d * KK + k];          // coalesced: lanes = consecutive k
        eT[(size_t)k * DD + d] = v;
        unsigned short h = bf16_rn_bits(v);
        float lo = v - bf16_bits_to_f(h);
        int dh = d >> 5, g = (d & 31) >> 3, j = d & 7;
        size_t idx = ((size_t)((tile * 2 + dh) * 64 + g * 16 + r)) * 8 + j;
        ehp[idx] = h;
        elp[idx] = bf16_rn_bits(lo);
        s = fmaf(v, v, s);
    }
    part[dq][kl] = s;
    __syncthreads();
    if (dq == 0) enorm[k] = part[0][kl] + part[1][kl] + part[2][kl] + part[3][kl];
}

// 1024 blocks x 4 waves. Block = 64 tokens. Wave (mg,kh): 32 tokens (2 M-tiles) x 512 codes.
__global__ __launch_bounds__(256) void vq_mfma(const float* __restrict__ inp,
                                               const unsigned short* __restrict__ ehp,
                                               const unsigned short* __restrict__ elp,
                                               const float* __restrict__ eT,
                                               const float* __restrict__ enorm,
                                               float* __restrict__ outQ,
                                               float* __restrict__ outDiff,
                                               float* __restrict__ outInd,
                                               int* __restrict__ fcount,
                                               int* __restrict__ flist) {
    __shared__ float s_b1[64][2];
    __shared__ float s_b2[64][2];
    __shared__ int   s_k1[64][2];
    __shared__ int   s_kwin[64];

    int tid  = threadIdx.x;
    int wave = tid >> 6, lane = tid & 63;
    int g = lane >> 4, r = lane & 15;
    int mg = wave >> 1, kh = wave & 1;
    int tokBlk = blockIdx.x * 64;
    int tok0   = tokBlk + mg * 32;            // this wave's 32 tokens

    // A-frags: [m-tile][D-half]; lane (g,r) holds x[tok0+16m+r][32dh+8g..+8)
    short8v a_hi[2][2], a_lo[2][2];
#pragma unroll
    for (int m = 0; m < 2; ++m) {
        const float* xrow = inp + (size_t)(tok0 + 16 * m + r) * DD + 8 * g;
#pragma unroll
        for (int dh = 0; dh < 2; ++dh) {
            float4 v0 = *(const float4*)(xrow + 32 * dh);
            float4 v1 = *(const float4*)(xrow + 32 * dh + 4);
            float xv[8] = {v0.x, v0.y, v0.z, v0.w, v1.x, v1.y, v1.z, v1.w};
#pragma unroll
            for (int j = 0; j < 8; ++j) {
                unsigned short h = bf16_rn_bits(xv[j]);
                float lo = xv[j] - bf16_bits_to_f(h);
                a_hi[m][dh][j] = (short)h;
                a_lo[m][dh][j] = (short)bf16_rn_bits(lo);
            }
        }
    }

    float best1[2][4], best2[2][4];
    int k1[2][4];
#pragma unroll
    for (int m = 0; m < 2; ++m)
#pragma unroll
        for (int j = 0; j < 4; ++j) { best1[m][j] = 3.4e38f; best2[m][j] = 3.4e38f; k1[m][j] = 0; }

    const short8v* hp = (const short8v*)ehp;   // [tile*2+dh][lane] of 16B frags
    const short8v* lp = (const short8v*)elp;

#pragma unroll 2
    for (int t = 0; t < KK / 32; ++t) {       // 32 iterations over this wave's K-half
        int tg = kh * 32 + t;                 // global 16-code tile
        int c  = tg * 16 + r;                 // this lane's code (B col r)
        short8v bhi0 = hp[(tg * 2 + 0) * 64 + lane];   // coalesced 1KB/wave
        short8v bhi1 = hp[(tg * 2 + 1) * 64 + lane];
        short8v blo0 = lp[(tg * 2 + 0) * 64 + lane];
        short8v blo1 = lp[(tg * 2 + 1) * 64 + lane];
        float en = enorm[c];

        f32x4 accA0 = {0.f,0.f,0.f,0.f}, accA1 = {0.f,0.f,0.f,0.f};
        f32x4 accB0 = {0.f,0.f,0.f,0.f}, accB1 = {0.f,0.f,0.f,0.f};
        // 12 MFMAs, 4 independent chains interleaved (hi*hi + hi*lo + lo*hi)
        accA0 = __builtin_amdgcn_mfma_f32_16x16x32_bf16(a_hi[0][0], bhi0, accA0, 0, 0, 0);
        accA1 = __builtin_amdgcn_mfma_f32_16x16x32_bf16(a_hi[1][0], bhi0, accA1, 0, 0, 0);
        accB0 = __builtin_amdgcn_mfma_f32_16x16x32_bf16(a_lo[0][0], bhi0, accB0, 0, 0, 0);
        accB1 = __builtin_amdgcn_mfma_f32_16x16x32_bf16(a_lo[1][0], bhi0, accB1, 0, 0, 0);
        accA0 = __builtin_amdgcn_mfma_f32_16x16x32_bf16(a_hi[0][1], bhi1, accA0, 0, 0, 0);
        accA1 = __builtin_amdgcn_mfma_f32_16x16x32_bf16(a_hi[1][1], bhi1, accA1, 0, 0, 0);
        accB0 = __builtin_amdgcn_mfma_f32_16x16x32_bf16(a_lo[0][1], bhi1, accB0, 0, 0, 0);
        accB1 = __builtin_amdgcn_mfma_f32_16x16x32_bf16(a_lo[1][1], bhi1, accB1, 0, 0, 0);
        accA0 = __builtin_amdgcn_mfma_f32_16x16x32_bf16(a_hi[0][0], blo0, accA0, 0, 0, 0);
        accA1 = __builtin_amdgcn_mfma_f32_16x16x32_bf16(a_hi[1][0], blo0, accA1, 0, 0, 0);
        accA0 = __builtin_amdgcn_mfma_f32_16x16x32_bf16(a_hi[0][1], blo1, accA0, 0, 0, 0);
        accA1 = __builtin_amdgcn_mfma_f32_16x16x32_bf16(a_hi[1][1], blo1, accA1, 0, 0, 0);

#pragma unroll
        for (int m = 0; m < 2; ++m) {
            const f32x4& aA = m ? accA1 : accA0;
            const f32x4& aB = m ? accB1 : accB0;
#pragma unroll
            for (int j = 0; j < 4; ++j) {     // C row = 4g+j -> token tok0+16m+4g+j
                float dist = fmaf(-2.f, aA[j] + aB[j], en);
                bool lt1 = dist < best1[m][j];
                bool lt2 = dist < best2[m][j];
                float nb2 = lt1 ? best1[m][j] : (lt2 ? dist : best2[m][j]);
                best1[m][j] = lt1 ? dist : best1[m][j];
                k1[m][j]    = lt1 ? c    : k1[m][j];
                best2[m][j] = nb2;
            }
        }
    }

    // merge across the 16 lanes of each group (xor masks < 16 stay in-group)
#pragma unroll
    for (int msk = 1; msk < 16; msk <<= 1) {
#pragma unroll
        for (int m = 0; m < 2; ++m)
#pragma unroll
            for (int j = 0; j < 4; ++j) {
                float ob1 = __shfl_xor(best1[m][j], msk, 64);
                float ob2 = __shfl_xor(best2[m][j], msk, 64);
                int   ok  = __shfl_xor(k1[m][j],   msk, 64);
                bool takeOther = (ob1 < best1[m][j]) || (ob1 == best1[m][j] && ok < k1[m][j]);
                float lose = takeOther ? best1[m][j] : ob1;
                best1[m][j] = takeOther ? ob1 : best1[m][j];
                k1[m][j]    = takeOther ? ok  : k1[m][j];
                best2[m][j] = fminf(fminf(best2[m][j], ob2), lose);
            }
    }

    if (r == 0) {
#pragma unroll
        for (int m = 0; m < 2; ++m)
#pragma unroll
            for (int j = 0; j < 4; ++j) {
                int tl = mg * 32 + m * 16 + 4 * g + j;    // token within block
                s_b1[tl][kh] = best1[m][j];
                s_b2[tl][kh] = best2[m][j];
                s_k1[tl][kh] = k1[m][j];
            }
    }
    __syncthreads();

    // threads 0..63: merge the two K-halves for token tid (half 0 has lower k: ties -> half 0)
    if (tid < 64) {
        float b1a = s_b1[tid][0], b2a = s_b2[tid][0];
        float b1b = s_b1[tid][1], b2b = s_b2[tid][1];
        int   ka  = s_k1[tid][0], kb  = s_k1[tid][1];
        float nb1, nb2; int nk;
        if (b1b < b1a) { nb1 = b1b; nk = kb; nb2 = fminf(b1a, b2b); }
        else           { nb1 = b1a; nk = ka; nb2 = fminf(b2a, b1b); }
        int tok = tokBlk + tid;
        outInd[tok]  = (float)nk;
        s_kwin[tid]  = nk;
        if (nb2 - nb1 < 0.02f) {              // near-tie: queue exact f64 rescore
            int idx = atomicAdd(fcount, 1);
            if (idx < FCAP) flist[idx] = tok;
        }
    }
    __syncthreads();

    // epilogue: wave w writes block-tokens [16w, 16w+16), one 256B row per step
#pragma unroll
    for (int tt = 0; tt < 16; ++tt) {
        int tl = wave * 16 + tt;
        int k  = s_kwin[tl];                               // uniform LDS broadcast
        float ev = eT[(size_t)k * DD + lane];
        float xv = inp[(size_t)(tokBlk + tl) * DD + lane];
        float d  = ev - xv;
        outQ[(size_t)(tokBlk + tl) * DD + lane]    = ev;
        outDiff[(size_t)(tokBlk + tl) * DD + lane] = d * d;
    }
}

// 256 blocks x 4 waves grid-stride the flagged-token list; exact f64 rescan,
// reading embed[D][K] directly (transposed -> coalesced across lanes).
__global__ __launch_bounds__(256) void vq_fixup(const float* __restrict__ inp,
                                                const float* __restrict__ embed,
                                                const float* __restrict__ eT,
                                                const int* __restrict__ fcount,
                                                const int* __restrict__ flist,
                                                float* __restrict__ outQ,
                                                float* __restrict__ outDiff,
                                                float* __restrict__ outInd) {
    int wid  = blockIdx.x * 4 + (threadIdx.x >> 6);   // 1024 waves
    int lane = threadIdx.x & 63;
    int nt   = *fcount;
    if (nt > FCAP) nt = FCAP;

    for (int i = wid; i < nt; i += 1024) {
        int n = flist[i];

        float x[DD];                                   // wave-uniform x row
        const float4* xp = (const float4*)(inp + (size_t)n * DD);
#pragma unroll
        for (int q = 0; q < DD / 4; ++q) {
            float4 v = xp[q];
            x[4 * q + 0] = v.x; x[4 * q + 1] = v.y;
            x[4 * q + 2] = v.z; x[4 * q + 3] = v.w;
        }

        double bestd = 1e300;
        int bk = 0;
        for (int c = 0; c < KK / 64; ++c) {
            int k = c * 64 + lane;                     // lane-local code, k ascending
            const float* ecol = embed + k;             // embed[d*KK + k]: coalesced
            double acc0 = 0.0, acc1 = 0.0;
#pragma unroll
            for (int d = 0; d < DD; d += 2) {
                float e0 = ecol[(size_t)d * KK];
                float e1 = ecol[(size_t)(d + 1) * KK];
                double dx0 = (double)x[d]     - (double)e0;
                double dx1 = (double)x[d + 1] - (double)e1;
                acc0 = fma(dx0, dx0, acc0);
                acc1 = fma(dx1, dx1, acc1);
            }
            double acc = acc0 + acc1;
            if (acc < bestd) { bestd = acc; bk = k; }  // strict <, k ascending per lane
        }
        // cross-lane argmin, ties -> smaller k (np.argmin first-occurrence)
        for (int off = 32; off > 0; off >>= 1) {
            double od = __shfl_xor(bestd, off);
            int    ok = __shfl_xor(bk, off);
            if (od < bestd || (od == bestd && ok < bk)) { bestd = od; bk = ok; }
        }
        float q  = eT[(size_t)bk * DD + lane];
        float xv = inp[(size_t)n * DD + lane];
        float dd = q - xv;
        outQ[(size_t)n * DD + lane]    = q;
        outDiff[(size_t)n * DD + lane] = dd * dd;
        if (lane == 0) outInd[n] = (float)bk;
    }
}

extern "C" void kernel_launch(void* const* d_in, const int* in_sizes, int n_in,
                              void* d_out, int out_size, void* d_ws, size_t ws_size,
                              hipStream_t stream) {
    const float* inp   = (const float*)d_in[0];
    const float* embed = (const float*)d_in[1];
    float* outQ    = (float*)d_out;
    float* outDiff = outQ + (size_t)NN * DD;
    float* outInd  = outDiff + (size_t)NN * DD;

    char* ws = (char*)d_ws;
    float*          eT     = (float*)(ws);
    unsigned short* ehp    = (unsigned short*)(ws + 262144);
    unsigned short* elp    = (unsigned short*)(ws + 393216);
    float*          enorm  = (float*)(ws + 524288);
    int*            fcount = (int*)(ws + 528384);
    int*            flist  = (int*)(ws + 528400);

    vq_prep <<<16,   256, 0, stream>>>(embed, eT, ehp, elp, enorm, fcount);
    vq_mfma <<<1024, 256, 0, stream>>>(inp, ehp, elp, eT, enorm, outQ, outDiff, outInd, fcount, flist);
    vq_fixup<<<256,  256, 0, stream>>>(inp, embed, eT, fcount, flist, outQ, outDiff, outInd);
}